// Round 12
// baseline (293.175 us; speedup 1.0000x reference)
//
#include <hip/hip_runtime.h>

#define HEADS 4
#define HID 64
#define CH1 256   // HEADS*HID
#define CLS 6
#define H2S 8     // h2 row stride (padded for aligned loads)
#define NSLOPE 0.2f

typedef short bf16x8 __attribute__((ext_vector_type(8)));
typedef float f32x4 __attribute__((ext_vector_type(4)));

__device__ __forceinline__ float leaky(float x) {
  return (x >= 0.f) ? x : NSLOPE * x;
}

__device__ __forceinline__ ushort f2bf(float f) {
  unsigned u = __float_as_uint(f);
  unsigned r = (u + 0x7FFFu + ((u >> 16) & 1u)) >> 16;
  return (ushort)r;
}

__device__ __forceinline__ float bf2f(ushort u) {
  return __uint_as_float((unsigned)u << 16);
}

// ---- fused: edge-count (CSR degree) + W1 -> w1t bf16 transpose ----
__global__ void k_count_cvt(const int* __restrict__ ei, int E, int Etot,
                            int* __restrict__ cnt, int eb,
                            const float* __restrict__ W1, ushort* __restrict__ w1t) {
  int b = blockIdx.x;
  if (b < eb) {
    int e = b * 256 + threadIdx.x;
    if (e >= Etot) return;
    int d = (e < E) ? ei[E + e] : e - E;
    atomicAdd(&cnt[d], 1);
  } else {
    int t = (b - eb) * 256 + threadIdx.x;   // t = k*256 + c
    if (t >= 512 * 256) return;
    int k = t >> 8, c = t & 255;
    w1t[c * 512 + k] = f2bf(W1[t]);
  }
}

// ---- GEMM1: ALL operands direct global->reg. NO LDS, NO barriers. ----
// block 256 = 4 waves; BM=64, BN=256, BK=32; wave w owns cols w*64..+63 = head w
// A-tile (64 rows x 2KB) is read by all 4 waves -> L1/L2-hot redundancy.
__global__ __launch_bounds__(256, 2) void k_gemm1_mfma(
    const float* __restrict__ x,     // [M][512] fp32
    const ushort* __restrict__ w1t,  // [256][512] bf16
    const float* __restrict__ a_src, const float* __restrict__ a_dst,
    ushort* __restrict__ h1b, float* __restrict__ es, float* __restrict__ ed,
    int M) {
  int t = threadIdx.x;
  int wid = t >> 6, lane = t & 63;
  int brow = blockIdx.x * 64;
  int l15 = lane & 15, g = lane >> 4;

  // A row pointers for the 4 m-frags: lane reads 8 consecutive fp32 (32B)
  const float* ap[4];
#pragma unroll
  for (int m = 0; m < 4; ++m) {
    int r = brow + m * 16 + l15; if (r >= M) r = M - 1;
    ap[m] = x + (size_t)r * 512 + g * 8;
  }
  // B fragment pointers: 16 contiguous bytes per (n, kt)
  const ushort* bp[4];
#pragma unroll
  for (int n = 0; n < 4; ++n)
    bp[n] = w1t + (size_t)(wid * 64 + n * 16 + l15) * 512 + g * 8;

  f32x4 acc[4][4] = {};

  // register pipeline: next-step raw operands
  f32x4 nLo[4], nHi[4];
  bf16x8 nB[4];
#pragma unroll
  for (int m = 0; m < 4; ++m) {
    nLo[m] = *(const f32x4*)(ap[m]);
    nHi[m] = *(const f32x4*)(ap[m] + 4);
  }
#pragma unroll
  for (int n = 0; n < 4; ++n) nB[n] = *(const bf16x8*)bp[n];

#pragma unroll
  for (int kt = 0; kt < 16; ++kt) {
    // convert current A (consumes nLo/nHi before they are overwritten)
    bf16x8 av[4], bv[4];
#pragma unroll
    for (int m = 0; m < 4; ++m) {
      union { unsigned u[4]; bf16x8 b; } cv;
      asm("v_cvt_pk_bf16_f32 %0, %1, %2" : "=v"(cv.u[0]) : "v"(nLo[m][0]), "v"(nLo[m][1]));
      asm("v_cvt_pk_bf16_f32 %0, %1, %2" : "=v"(cv.u[1]) : "v"(nLo[m][2]), "v"(nLo[m][3]));
      asm("v_cvt_pk_bf16_f32 %0, %1, %2" : "=v"(cv.u[2]) : "v"(nHi[m][0]), "v"(nHi[m][1]));
      asm("v_cvt_pk_bf16_f32 %0, %1, %2" : "=v"(cv.u[3]) : "v"(nHi[m][2]), "v"(nHi[m][3]));
      av[m] = cv.b;
    }
#pragma unroll
    for (int n = 0; n < 4; ++n) bv[n] = nB[n];
    // issue next-step loads (overlap the MFMAs below)
    if (kt < 15) {
#pragma unroll
      for (int m = 0; m < 4; ++m) {
        nLo[m] = *(const f32x4*)(ap[m] + (kt + 1) * 32);
        nHi[m] = *(const f32x4*)(ap[m] + (kt + 1) * 32 + 4);
      }
#pragma unroll
      for (int n = 0; n < 4; ++n)
        nB[n] = *(const bf16x8*)(bp[n] + (kt + 1) * 32);
    }
#pragma unroll
    for (int m = 0; m < 4; ++m)
#pragma unroll
      for (int n = 0; n < 4; ++n)
        acc[m][n] = __builtin_amdgcn_mfma_f32_16x16x32_bf16(av[m], bv[n], acc[m][n], 0, 0, 0);
  }

  // epilogue: bf16 h write + per-row es/ed for head `wid`
  float as4[4], ad4[4];
#pragma unroll
  for (int n = 0; n < 4; ++n) {
    int c = wid * 64 + n * 16 + l15;
    as4[n] = a_src[c];
    ad4[n] = a_dst[c];
  }
  int rbase = g * 4;
#pragma unroll
  for (int m = 0; m < 4; ++m) {
#pragma unroll
    for (int r = 0; r < 4; ++r) {
      int grow = brow + m * 16 + rbase + r;
      bool ok = grow < M;
      float ps = 0.f, pd = 0.f;
#pragma unroll
      for (int n = 0; n < 4; ++n) {
        float v = acc[m][n][r];
        ps += v * as4[n];
        pd += v * ad4[n];
        if (ok) h1b[(size_t)grow * CH1 + wid * 64 + n * 16 + l15] = f2bf(v);
      }
#pragma unroll
      for (int o = 1; o < 16; o <<= 1) {
        ps += __shfl_xor(ps, o);
        pd += __shfl_xor(pd, o);
      }
      if (l15 == 0 && ok) {
        es[grow * HEADS + wid] = ps;
        ed[grow * HEADS + wid] = pd;
      }
    }
  }
}

// scan1 also re-zeroes cursor (used as deg input) for the scatter pass
__global__ __launch_bounds__(256) void k_scan1(int* __restrict__ deg,
    int* __restrict__ rowptr, int* __restrict__ bsum, int n) {
  int i = blockIdx.x * 256 + threadIdx.x;
  int v = (i < n) ? deg[i] : 0;
  if (i < n) deg[i] = 0;
  int lane = threadIdx.x & 63, wave = threadIdx.x >> 6;
  int incl = v;
#pragma unroll
  for (int o = 1; o < 64; o <<= 1) {
    int u = __shfl_up(incl, o);
    if (lane >= o) incl += u;
  }
  __shared__ int ws4[4];
  if (lane == 63) ws4[wave] = incl;
  __syncthreads();
  if (threadIdx.x == 0) {
    int run = 0;
    for (int w = 0; w < 4; ++w) { int x = ws4[w]; ws4[w] = run; run += x; }
    bsum[blockIdx.x] = run;
  }
  __syncthreads();
  if (i < n) rowptr[i] = incl - v + ws4[wave];
}

// scan3 with inline scan2: each block sums bsum[0..blockIdx) itself
__global__ __launch_bounds__(256) void k_scan3(int* __restrict__ rowptr,
    const int* __restrict__ bsum, int n, int Etot, int nb) {
  int t = threadIdx.x;
  int b = blockIdx.x;
  int v = (t < b && t < nb) ? bsum[t] : 0;
  int lane = t & 63, wave = t >> 6;
#pragma unroll
  for (int o = 32; o; o >>= 1) v += __shfl_xor(v, o);
  __shared__ int ws4[4];
  if (lane == 0) ws4[wave] = v;
  __syncthreads();
  int base = ws4[0] + ws4[1] + ws4[2] + ws4[3];
  int i = b * 256 + t;
  if (i < n) rowptr[i] += base;
  if (i == 0) rowptr[n] = Etot;
}

__global__ void k_scatter(const int* __restrict__ ei, int E, int Etot,
    const int* __restrict__ rowptr, int* __restrict__ cursor,
    int* __restrict__ esrc) {
  int e = blockIdx.x * blockDim.x + threadIdx.x;
  if (e >= Etot) return;
  int s, d;
  if (e < E) { s = ei[e]; d = ei[E + e]; } else { s = d = e - E; }
  int pos = rowptr[d] + atomicAdd(&cursor[d], 1);
  esrc[pos] = s;
}

// ---- layer-1 softmax(no-max)+aggregate+bias+ELU + GEMM2 + layer-2 scores ----
__global__ __launch_bounds__(256) void k_agg1_csr(const int* __restrict__ rowptr,
    const int* __restrict__ esrc, const float* __restrict__ es,
    const float* __restrict__ ed, const ushort* __restrict__ h1b,
    const float* __restrict__ b1, const float* __restrict__ W2,
    const float* __restrict__ a_src2, const float* __restrict__ a_dst2,
    float* __restrict__ h2, float* __restrict__ es2, float* __restrict__ ed2,
    int Nn) {
  __shared__ int   spi[4][64];
  __shared__ float spp[4][64 * 4];
  int wid = threadIdx.x >> 6, lane = threadIdx.x & 63;
  int ch = lane * 4;
  float w2s[4][CLS];
#pragma unroll
  for (int c = 0; c < 4; ++c)
#pragma unroll
    for (int j = 0; j < CLS; ++j)
      w2s[c][j] = W2[(ch + c) * CLS + j];

  int d = blockIdx.x * 4 + wid;
  if (d >= Nn) return;
  int beg = rowptr[d], end = rowptr[d + 1];
  float4 edv = *(const float4*)&ed[d * 4];
  int myhead = lane >> 4;
  const char* hcb = (const char*)h1b + (size_t)ch * 2;

  // single pass: chunked dedup + accumulate (no max pass)
  float4 acc = make_float4(0.f, 0.f, 0.f, 0.f);
  float4 den4 = make_float4(0.f, 0.f, 0.f, 0.f);
  const float* pp = &spp[wid][0];
  for (int c0 = beg; c0 < end; c0 += 64) {
    int i = c0 + lane;
    int s = 0;
    float4 p = make_float4(0.f, 0.f, 0.f, 0.f);
    if (i < end) {
      s = esrc[i];
      float4 e4 = *(const float4*)&es[s * 4];
      p.x = __expf(leaky(e4.x + edv.x));
      p.y = __expf(leaky(e4.y + edv.y));
      p.z = __expf(leaky(e4.z + edv.z));
      p.w = __expf(leaky(e4.w + edv.w));
    }
    den4.x += p.x; den4.y += p.y; den4.z += p.z; den4.w += p.w;
    spi[wid][lane] = s << 9;                // row BYTE offset (s * CH1 * 2)
    *(float4*)&spp[wid][lane * 4] = p;      // wave-private, no barrier
    int cl = min(64, end - c0);
    int j = 0;
    for (; j + 3 < cl; j += 4) {
      int o0 = spi[wid][j],     o1 = spi[wid][j + 1];
      int o2 = spi[wid][j + 2], o3 = spi[wid][j + 3];
      float p0 = pp[j * 4 + myhead],       p1 = pp[(j + 1) * 4 + myhead];
      float p2 = pp[(j + 2) * 4 + myhead], p3 = pp[(j + 3) * 4 + myhead];
      ushort4 v0 = *(const ushort4*)(hcb + o0);
      ushort4 v1 = *(const ushort4*)(hcb + o1);
      ushort4 v2 = *(const ushort4*)(hcb + o2);
      ushort4 v3 = *(const ushort4*)(hcb + o3);
      acc.x += p0 * bf2f(v0.x) + p1 * bf2f(v1.x) + p2 * bf2f(v2.x) + p3 * bf2f(v3.x);
      acc.y += p0 * bf2f(v0.y) + p1 * bf2f(v1.y) + p2 * bf2f(v2.y) + p3 * bf2f(v3.y);
      acc.z += p0 * bf2f(v0.z) + p1 * bf2f(v1.z) + p2 * bf2f(v2.z) + p3 * bf2f(v3.z);
      acc.w += p0 * bf2f(v0.w) + p1 * bf2f(v1.w) + p2 * bf2f(v2.w) + p3 * bf2f(v3.w);
    }
    for (; j < cl; ++j) {
      int oj = spi[wid][j];
      float pj = pp[j * 4 + myhead];
      ushort4 v = *(const ushort4*)(hcb + oj);
      acc.x += pj * bf2f(v.x);
      acc.y += pj * bf2f(v.y);
      acc.z += pj * bf2f(v.z);
      acc.w += pj * bf2f(v.w);
    }
  }
#pragma unroll
  for (int o = 32; o; o >>= 1) {
    den4.x += __shfl_xor(den4.x, o);
    den4.y += __shfl_xor(den4.y, o);
    den4.z += __shfl_xor(den4.z, o);
    den4.w += __shfl_xor(den4.w, o);
  }
  float den = (myhead == 0) ? den4.x : (myhead == 1) ? den4.y
            : (myhead == 2) ? den4.z : den4.w;
  float4 b4 = *(const float4*)&b1[ch];
  float4 r;
  r.x = acc.x / den + b4.x; r.x = (r.x > 0.f) ? r.x : expm1f(r.x);
  r.y = acc.y / den + b4.y; r.y = (r.y > 0.f) ? r.y : expm1f(r.y);
  r.z = acc.z / den + b4.z; r.z = (r.z > 0.f) ? r.z : expm1f(r.z);
  r.w = acc.w / den + b4.w; r.w = (r.w > 0.f) ? r.w : expm1f(r.w);

  // fused GEMM2: q[j] = row · W2[:,j], reduced across the wave
  float q0 = r.x * w2s[0][0] + r.y * w2s[1][0] + r.z * w2s[2][0] + r.w * w2s[3][0];
  float q1 = r.x * w2s[0][1] + r.y * w2s[1][1] + r.z * w2s[2][1] + r.w * w2s[3][1];
  float q2 = r.x * w2s[0][2] + r.y * w2s[1][2] + r.z * w2s[2][2] + r.w * w2s[3][2];
  float q3 = r.x * w2s[0][3] + r.y * w2s[1][3] + r.z * w2s[2][3] + r.w * w2s[3][3];
  float q4 = r.x * w2s[0][4] + r.y * w2s[1][4] + r.z * w2s[2][4] + r.w * w2s[3][4];
  float q5 = r.x * w2s[0][5] + r.y * w2s[1][5] + r.z * w2s[2][5] + r.w * w2s[3][5];
#pragma unroll
  for (int o = 32; o; o >>= 1) {
    q0 += __shfl_xor(q0, o); q1 += __shfl_xor(q1, o); q2 += __shfl_xor(q2, o);
    q3 += __shfl_xor(q3, o); q4 += __shfl_xor(q4, o); q5 += __shfl_xor(q5, o);
  }
  if (lane == 0) {
    float* h2r = &h2[(size_t)d * H2S];
    h2r[0] = q0; h2r[1] = q1; h2r[2] = q2; h2r[3] = q3; h2r[4] = q4; h2r[5] = q5;
    es2[d] = q0 * a_src2[0] + q1 * a_src2[1] + q2 * a_src2[2]
           + q3 * a_src2[3] + q4 * a_src2[4] + q5 * a_src2[5];
    ed2[d] = q0 * a_dst2[0] + q1 * a_dst2[1] + q2 * a_dst2[2]
           + q3 * a_dst2[3] + q4 * a_dst2[4] + q5 * a_dst2[5];
  }
}

// ---- layer-2 softmax(no-max)+aggregate+bias+log_softmax: 8 lanes per node ----
__global__ __launch_bounds__(256) void k_l2(const int* __restrict__ rowptr,
    const int* __restrict__ esrc, const float* __restrict__ es2,
    const float* __restrict__ ed2, const float* __restrict__ h2,
    const float* __restrict__ b2, float* __restrict__ out, int Nn) {
  int t = threadIdx.x;
  int grp = t >> 3, sl = t & 7;       // 32 groups/block, 8 lanes/group
  int n = blockIdx.x * 32 + grp;
  if (n >= Nn) return;
  int beg = rowptr[n], end = rowptr[n + 1];
  float edv = ed2[n];
  float den = 0.f, a0 = 0.f, a1 = 0.f, a2 = 0.f, a3 = 0.f, a4 = 0.f, a5 = 0.f;
  for (int i = beg + sl; i < end; i += 8) {
    int s = esrc[i];
    float p = __expf(leaky(es2[s] + edv));
    den += p;
    const float* hr = &h2[(size_t)s * H2S];
    float4 v0 = *(const float4*)hr;
    float2 v1 = *(const float2*)(hr + 4);
    a0 += p * v0.x; a1 += p * v0.y; a2 += p * v0.z;
    a3 += p * v0.w; a4 += p * v1.x; a5 += p * v1.y;
  }
#pragma unroll
  for (int o = 1; o < 8; o <<= 1) {
    den += __shfl_xor(den, o);
    a0 += __shfl_xor(a0, o); a1 += __shfl_xor(a1, o); a2 += __shfl_xor(a2, o);
    a3 += __shfl_xor(a3, o); a4 += __shfl_xor(a4, o); a5 += __shfl_xor(a5, o);
  }
  if (sl == 0) {
    float v[CLS];
    v[0] = a0 / den + b2[0]; v[1] = a1 / den + b2[1]; v[2] = a2 / den + b2[2];
    v[3] = a3 / den + b2[3]; v[4] = a4 / den + b2[4]; v[5] = a5 / den + b2[5];
    float mx = -1e30f;
#pragma unroll
    for (int j = 0; j < CLS; ++j) mx = fmaxf(mx, v[j]);
    float sum = 0.f;
#pragma unroll
    for (int j = 0; j < CLS; ++j) sum += __expf(v[j] - mx);
    float l = mx + logf(sum);
#pragma unroll
    for (int j = 0; j < CLS; ++j) out[n * CLS + j] = v[j] - l;
  }
}

extern "C" void kernel_launch(void* const* d_in, const int* in_sizes, int n_in,
                              void* d_out, int out_size, void* d_ws, size_t ws_size,
                              hipStream_t stream) {
  const float* x      = (const float*)d_in[0];
  const int*   ei     = (const int*)d_in[1];
  const float* W1     = (const float*)d_in[2];
  const float* a_src1 = (const float*)d_in[3];
  const float* a_dst1 = (const float*)d_in[4];
  const float* b1     = (const float*)d_in[5];
  const float* W2     = (const float*)d_in[6];
  const float* a_src2 = (const float*)d_in[7];
  const float* a_dst2 = (const float*)d_in[8];
  const float* b2     = (const float*)d_in[9];
  float* out = (float*)d_out;

  const int IN_F = 512;
  int N = in_sizes[0] / IN_F;      // 50000
  int E = in_sizes[1] / 2;         // 800000
  int Etot = E + N;

  // ---- workspace partition ----
  float* ws = (float*)d_ws;
  size_t off = 0;
  ushort* h1b = (ushort*)(ws + off); off += (size_t)N * CH1;   // only half used
  float* es1  = ws + off; off += (size_t)N * HEADS;
  float* ed1  = ws + off; off += (size_t)N * HEADS;
  float* h2   = ws + off; off += (size_t)N * H2S;
  float* es2  = ws + off; off += (size_t)N;
  float* ed2  = ws + off; off += (size_t)N;
  int* rowptr = (int*)(ws + off); off += (size_t)N + 1;
  int* cursor = (int*)(ws + off); off += (size_t)N;
  int* bsum   = (int*)(ws + off); off += 256;
  int* esrc   = (int*)(ws + off); off += (size_t)Etot;
  ushort* w1t = (ushort*)(ws + off); off += (512 * 256 * 2 + 3) / 4;

  int nb = (N + 255) / 256;
  int eb = (Etot + 255) / 256;

  // ---- CSR build (by dst) + W1 cvt, merged where independent ----
  hipMemsetAsync(cursor, 0, (size_t)N * 4, stream);
  k_count_cvt<<<eb + 512, 256, 0, stream>>>(ei, E, Etot, cursor, eb, W1, w1t);
  k_scan1<<<nb, 256, 0, stream>>>(cursor, rowptr, bsum, N);  // also zeroes cursor
  k_scan3<<<nb, 256, 0, stream>>>(rowptr, bsum, N, Etot, nb);
  k_scatter<<<eb, 256, 0, stream>>>(ei, E, Etot, rowptr, cursor, esrc);

  // ---- layer 1 ----
  k_gemm1_mfma<<<(N + 63) / 64, 256, 0, stream>>>(x, w1t, a_src1, a_dst1,
                                                  h1b, es1, ed1, N);
  k_agg1_csr<<<(N + 3) / 4, 256, 0, stream>>>(rowptr, esrc, es1, ed1, h1b, b1,
                                              W2, a_src2, a_dst2, h2, es2, ed2, N);

  // ---- layer 2 ----
  k_l2<<<(N + 31) / 32, 256, 0, stream>>>(rowptr, esrc, es2, ed2, h2, b2, out, N);
}

// Round 13
// 247.100 us; speedup vs baseline: 1.1865x; 1.1865x over previous
//
#include <hip/hip_runtime.h>

#define HEADS 4
#define HID 64
#define CH1 256   // HEADS*HID
#define CLS 6
#define H2S 8     // h2 row stride (padded for aligned loads)
#define NSLOPE 0.2f

typedef short bf16x8 __attribute__((ext_vector_type(8)));
typedef float f32x4 __attribute__((ext_vector_type(4)));

__device__ __forceinline__ float leaky(float x) {
  return (x >= 0.f) ? x : NSLOPE * x;
}

__device__ __forceinline__ ushort f2bf(float f) {
  unsigned u = __float_as_uint(f);
  unsigned r = (u + 0x7FFFu + ((u >> 16) & 1u)) >> 16;
  return (ushort)r;
}

__device__ __forceinline__ float bf2f(ushort u) {
  return __uint_as_float((unsigned)u << 16);
}

// ---- fused: edge-count (CSR degree) + W1 -> w1t bf16 transpose ----
__global__ void k_count_cvt(const int* __restrict__ ei, int E, int Etot,
                            int* __restrict__ cnt, int eb,
                            const float* __restrict__ W1, ushort* __restrict__ w1t) {
  int b = blockIdx.x;
  if (b < eb) {
    int e = b * 256 + threadIdx.x;
    if (e >= Etot) return;
    int d = (e < E) ? ei[E + e] : e - E;
    atomicAdd(&cnt[d], 1);
  } else {
    int t = (b - eb) * 256 + threadIdx.x;   // t = k*256 + c
    if (t >= 512 * 256) return;
    int k = t >> 8, c = t & 255;
    w1t[c * 512 + k] = f2bf(W1[t]);
  }
}

// ---- GEMM1: BM=64, BN=128 (grid x2 for occupancy), A reg-staged->LDS bf16,
//      B direct global->reg (w1t L2-resident). 4 waves, wave w: 4m x 2n frags.
__global__ __launch_bounds__(256, 4) void k_gemm1_mfma(
    const float* __restrict__ x,     // [M][512] fp32
    const ushort* __restrict__ w1t,  // [256][512] bf16
    const float* __restrict__ a_src, const float* __restrict__ a_dst,
    ushort* __restrict__ h1b, float* __restrict__ es, float* __restrict__ ed,
    int M) {
  __shared__ ushort ldsA[2][2048];   // [64][32] bf16, slot-swizzled
  __shared__ float pes[4][64], ped[4][64];
  int t = threadIdx.x;
  int wid = t >> 6, lane = t & 63;
  int brow = (blockIdx.x >> 1) * 64;
  int bcol = (blockIdx.x & 1) * 128;
  int l15 = lane & 15, g = lane >> 4;

  // A staging: thread t owns row rA=t>>2, write-slot q=t&3 (8 fp32 elems)
  int rA = t >> 2, qA = t & 3, lsA = qA ^ (rA & 3);
  int rowA = brow + rA; if (rowA >= M) rowA = M - 1;
  const float* srcA = x + (size_t)rowA * 512 + lsA * 8;
  int dAw = t * 8;

  int sw = ((g ^ (lane & 3)) << 3);
  int aoff[4];
#pragma unroll
  for (int m = 0; m < 4; ++m) aoff[m] = (m * 16 + l15) * 32 + sw;

  int colb = bcol + wid * 32;
  const ushort* bp[2];
#pragma unroll
  for (int n = 0; n < 2; ++n)
    bp[n] = w1t + (size_t)(colb + n * 16 + l15) * 512 + g * 8;

  f32x4 acc[4][2] = {};
  f32x4 aLo, aHi;

#define LOADA(kt) do { \
    aLo = *(const f32x4*)(srcA + (kt) * 32); \
    aHi = *(const f32x4*)(srcA + (kt) * 32 + 4); \
  } while (0)

#define WRITEA(buf) do { \
    union { unsigned u[4]; bf16x8 b; } cv; \
    asm("v_cvt_pk_bf16_f32 %0, %1, %2" : "=v"(cv.u[0]) : "v"(aLo[0]), "v"(aLo[1])); \
    asm("v_cvt_pk_bf16_f32 %0, %1, %2" : "=v"(cv.u[1]) : "v"(aLo[2]), "v"(aLo[3])); \
    asm("v_cvt_pk_bf16_f32 %0, %1, %2" : "=v"(cv.u[2]) : "v"(aHi[0]), "v"(aHi[1])); \
    asm("v_cvt_pk_bf16_f32 %0, %1, %2" : "=v"(cv.u[3]) : "v"(aHi[2]), "v"(aHi[3])); \
    *(bf16x8*)&ldsA[buf][dAw] = cv.b; \
  } while (0)

  bf16x8 bv[2][2];
#pragma unroll
  for (int n = 0; n < 2; ++n) bv[0][n] = *(const bf16x8*)bp[n];
  LOADA(0);
  WRITEA(0);
  __syncthreads();

#pragma unroll
  for (int kt = 0; kt < 16; ++kt) {
    const int cur = kt & 1;
    if (kt < 15) {
      LOADA(kt + 1);
#pragma unroll
      for (int n = 0; n < 2; ++n)
        bv[(kt + 1) & 1][n] = *(const bf16x8*)(bp[n] + (kt + 1) * 32);
    }
    bf16x8 av[4];
#pragma unroll
    for (int m = 0; m < 4; ++m) av[m] = *(const bf16x8*)&ldsA[cur][aoff[m]];
#pragma unroll
    for (int m = 0; m < 4; ++m)
#pragma unroll
      for (int n = 0; n < 2; ++n)
        acc[m][n] = __builtin_amdgcn_mfma_f32_16x16x32_bf16(av[m], bv[cur][n], acc[m][n], 0, 0, 0);
    if (kt < 15) WRITEA(cur ^ 1);
    __syncthreads();
  }
#undef LOADA
#undef WRITEA

  // epilogue: bf16 h write + per-row partial es/ed (this wave's 32 cols)
  float as2[2], ad2[2];
#pragma unroll
  for (int n = 0; n < 2; ++n) {
    int c = colb + n * 16 + l15;
    as2[n] = a_src[c];
    ad2[n] = a_dst[c];
  }
  int rbase = g * 4;
#pragma unroll
  for (int m = 0; m < 4; ++m) {
#pragma unroll
    for (int r = 0; r < 4; ++r) {
      int ri = m * 16 + rbase + r;
      int grow = brow + ri;
      bool ok = grow < M;
      float ps = 0.f, pd = 0.f;
#pragma unroll
      for (int n = 0; n < 2; ++n) {
        float v = acc[m][n][r];
        ps += v * as2[n];
        pd += v * ad2[n];
        if (ok) h1b[(size_t)grow * CH1 + colb + n * 16 + l15] = f2bf(v);
      }
#pragma unroll
      for (int o = 1; o < 16; o <<= 1) {
        ps += __shfl_xor(ps, o);
        pd += __shfl_xor(pd, o);
      }
      if (l15 == 0) {
        pes[wid][ri] = ps;
        ped[wid][ri] = pd;
      }
    }
  }
  __syncthreads();
  if (t < 128) {
    int ri = t & 63, hp = t >> 6;
    int grow = brow + ri;
    if (grow < M) {
      int head = (bcol >> 6) + hp;
      es[grow * HEADS + head] = pes[2 * hp][ri] + pes[2 * hp + 1][ri];
      ed[grow * HEADS + head] = ped[2 * hp][ri] + ped[2 * hp + 1][ri];
    }
  }
}

// scan1 also re-zeroes cursor (used as deg input) for the scatter pass
__global__ __launch_bounds__(256) void k_scan1(int* __restrict__ deg,
    int* __restrict__ rowptr, int* __restrict__ bsum, int n) {
  int i = blockIdx.x * 256 + threadIdx.x;
  int v = (i < n) ? deg[i] : 0;
  if (i < n) deg[i] = 0;
  int lane = threadIdx.x & 63, wave = threadIdx.x >> 6;
  int incl = v;
#pragma unroll
  for (int o = 1; o < 64; o <<= 1) {
    int u = __shfl_up(incl, o);
    if (lane >= o) incl += u;
  }
  __shared__ int ws4[4];
  if (lane == 63) ws4[wave] = incl;
  __syncthreads();
  if (threadIdx.x == 0) {
    int run = 0;
    for (int w = 0; w < 4; ++w) { int x = ws4[w]; ws4[w] = run; run += x; }
    bsum[blockIdx.x] = run;
  }
  __syncthreads();
  if (i < n) rowptr[i] = incl - v + ws4[wave];
}

// scan3 with inline scan2: each block sums bsum[0..blockIdx) itself
__global__ __launch_bounds__(256) void k_scan3(int* __restrict__ rowptr,
    const int* __restrict__ bsum, int n, int Etot, int nb) {
  int t = threadIdx.x;
  int b = blockIdx.x;
  int v = (t < b && t < nb) ? bsum[t] : 0;
  int lane = t & 63, wave = t >> 6;
#pragma unroll
  for (int o = 32; o; o >>= 1) v += __shfl_xor(v, o);
  __shared__ int ws4[4];
  if (lane == 0) ws4[wave] = v;
  __syncthreads();
  int base = ws4[0] + ws4[1] + ws4[2] + ws4[3];
  int i = b * 256 + t;
  if (i < n) rowptr[i] += base;
  if (i == 0) rowptr[n] = Etot;
}

__global__ void k_scatter(const int* __restrict__ ei, int E, int Etot,
    const int* __restrict__ rowptr, int* __restrict__ cursor,
    int* __restrict__ esrc) {
  int e = blockIdx.x * blockDim.x + threadIdx.x;
  if (e >= Etot) return;
  int s, d;
  if (e < E) { s = ei[e]; d = ei[E + e]; } else { s = d = e - E; }
  int pos = rowptr[d] + atomicAdd(&cursor[d], 1);
  esrc[pos] = s;
}

// ---- layer-1 softmax(no-max)+aggregate+bias+ELU + GEMM2 + layer-2 scores ----
__global__ __launch_bounds__(256) void k_agg1_csr(const int* __restrict__ rowptr,
    const int* __restrict__ esrc, const float* __restrict__ es,
    const float* __restrict__ ed, const ushort* __restrict__ h1b,
    const float* __restrict__ b1, const float* __restrict__ W2,
    const float* __restrict__ a_src2, const float* __restrict__ a_dst2,
    float* __restrict__ h2, float* __restrict__ es2, float* __restrict__ ed2,
    int Nn) {
  __shared__ int   spi[4][64];
  __shared__ float spp[4][64 * 4];
  int wid = threadIdx.x >> 6, lane = threadIdx.x & 63;
  int ch = lane * 4;
  float w2s[4][CLS];
#pragma unroll
  for (int c = 0; c < 4; ++c)
#pragma unroll
    for (int j = 0; j < CLS; ++j)
      w2s[c][j] = W2[(ch + c) * CLS + j];

  int d = blockIdx.x * 4 + wid;
  if (d >= Nn) return;
  int beg = rowptr[d], end = rowptr[d + 1];
  float4 edv = *(const float4*)&ed[d * 4];
  int myhead = lane >> 4;
  const char* hcb = (const char*)h1b + (size_t)ch * 2;

  // single pass: chunked dedup + accumulate (no max pass)
  float4 acc = make_float4(0.f, 0.f, 0.f, 0.f);
  float4 den4 = make_float4(0.f, 0.f, 0.f, 0.f);
  const float* pp = &spp[wid][0];
  for (int c0 = beg; c0 < end; c0 += 64) {
    int i = c0 + lane;
    int s = 0;
    float4 p = make_float4(0.f, 0.f, 0.f, 0.f);
    if (i < end) {
      s = esrc[i];
      float4 e4 = *(const float4*)&es[s * 4];
      p.x = __expf(leaky(e4.x + edv.x));
      p.y = __expf(leaky(e4.y + edv.y));
      p.z = __expf(leaky(e4.z + edv.z));
      p.w = __expf(leaky(e4.w + edv.w));
    }
    den4.x += p.x; den4.y += p.y; den4.z += p.z; den4.w += p.w;
    spi[wid][lane] = s << 9;                // row BYTE offset (s * CH1 * 2)
    *(float4*)&spp[wid][lane * 4] = p;      // wave-private, no barrier
    int cl = min(64, end - c0);
    int j = 0;
    for (; j + 3 < cl; j += 4) {
      int o0 = spi[wid][j],     o1 = spi[wid][j + 1];
      int o2 = spi[wid][j + 2], o3 = spi[wid][j + 3];
      float p0 = pp[j * 4 + myhead],       p1 = pp[(j + 1) * 4 + myhead];
      float p2 = pp[(j + 2) * 4 + myhead], p3 = pp[(j + 3) * 4 + myhead];
      ushort4 v0 = *(const ushort4*)(hcb + o0);
      ushort4 v1 = *(const ushort4*)(hcb + o1);
      ushort4 v2 = *(const ushort4*)(hcb + o2);
      ushort4 v3 = *(const ushort4*)(hcb + o3);
      acc.x += p0 * bf2f(v0.x) + p1 * bf2f(v1.x) + p2 * bf2f(v2.x) + p3 * bf2f(v3.x);
      acc.y += p0 * bf2f(v0.y) + p1 * bf2f(v1.y) + p2 * bf2f(v2.y) + p3 * bf2f(v3.y);
      acc.z += p0 * bf2f(v0.z) + p1 * bf2f(v1.z) + p2 * bf2f(v2.z) + p3 * bf2f(v3.z);
      acc.w += p0 * bf2f(v0.w) + p1 * bf2f(v1.w) + p2 * bf2f(v2.w) + p3 * bf2f(v3.w);
    }
    for (; j < cl; ++j) {
      int oj = spi[wid][j];
      float pj = pp[j * 4 + myhead];
      ushort4 v = *(const ushort4*)(hcb + oj);
      acc.x += pj * bf2f(v.x);
      acc.y += pj * bf2f(v.y);
      acc.z += pj * bf2f(v.z);
      acc.w += pj * bf2f(v.w);
    }
  }
#pragma unroll
  for (int o = 32; o; o >>= 1) {
    den4.x += __shfl_xor(den4.x, o);
    den4.y += __shfl_xor(den4.y, o);
    den4.z += __shfl_xor(den4.z, o);
    den4.w += __shfl_xor(den4.w, o);
  }
  float den = (myhead == 0) ? den4.x : (myhead == 1) ? den4.y
            : (myhead == 2) ? den4.z : den4.w;
  float4 b4 = *(const float4*)&b1[ch];
  float4 r;
  r.x = acc.x / den + b4.x; r.x = (r.x > 0.f) ? r.x : expm1f(r.x);
  r.y = acc.y / den + b4.y; r.y = (r.y > 0.f) ? r.y : expm1f(r.y);
  r.z = acc.z / den + b4.z; r.z = (r.z > 0.f) ? r.z : expm1f(r.z);
  r.w = acc.w / den + b4.w; r.w = (r.w > 0.f) ? r.w : expm1f(r.w);

  // fused GEMM2: q[j] = row · W2[:,j], reduced across the wave
  float q0 = r.x * w2s[0][0] + r.y * w2s[1][0] + r.z * w2s[2][0] + r.w * w2s[3][0];
  float q1 = r.x * w2s[0][1] + r.y * w2s[1][1] + r.z * w2s[2][1] + r.w * w2s[3][1];
  float q2 = r.x * w2s[0][2] + r.y * w2s[1][2] + r.z * w2s[2][2] + r.w * w2s[3][2];
  float q3 = r.x * w2s[0][3] + r.y * w2s[1][3] + r.z * w2s[2][3] + r.w * w2s[3][3];
  float q4 = r.x * w2s[0][4] + r.y * w2s[1][4] + r.z * w2s[2][4] + r.w * w2s[3][4];
  float q5 = r.x * w2s[0][5] + r.y * w2s[1][5] + r.z * w2s[2][5] + r.w * w2s[3][5];
#pragma unroll
  for (int o = 32; o; o >>= 1) {
    q0 += __shfl_xor(q0, o); q1 += __shfl_xor(q1, o); q2 += __shfl_xor(q2, o);
    q3 += __shfl_xor(q3, o); q4 += __shfl_xor(q4, o); q5 += __shfl_xor(q5, o);
  }
  if (lane == 0) {
    float* h2r = &h2[(size_t)d * H2S];
    h2r[0] = q0; h2r[1] = q1; h2r[2] = q2; h2r[3] = q3; h2r[4] = q4; h2r[5] = q5;
    es2[d] = q0 * a_src2[0] + q1 * a_src2[1] + q2 * a_src2[2]
           + q3 * a_src2[3] + q4 * a_src2[4] + q5 * a_src2[5];
    ed2[d] = q0 * a_dst2[0] + q1 * a_dst2[1] + q2 * a_dst2[2]
           + q3 * a_dst2[3] + q4 * a_dst2[4] + q5 * a_dst2[5];
  }
}

// ---- layer-2 softmax(no-max)+aggregate+bias+log_softmax: 8 lanes per node ----
__global__ __launch_bounds__(256) void k_l2(const int* __restrict__ rowptr,
    const int* __restrict__ esrc, const float* __restrict__ es2,
    const float* __restrict__ ed2, const float* __restrict__ h2,
    const float* __restrict__ b2, float* __restrict__ out, int Nn) {
  int t = threadIdx.x;
  int grp = t >> 3, sl = t & 7;       // 32 groups/block, 8 lanes/group
  int n = blockIdx.x * 32 + grp;
  if (n >= Nn) return;
  int beg = rowptr[n], end = rowptr[n + 1];
  float edv = ed2[n];
  float den = 0.f, a0 = 0.f, a1 = 0.f, a2 = 0.f, a3 = 0.f, a4 = 0.f, a5 = 0.f;
  for (int i = beg + sl; i < end; i += 8) {
    int s = esrc[i];
    float p = __expf(leaky(es2[s] + edv));
    den += p;
    const float* hr = &h2[(size_t)s * H2S];
    float4 v0 = *(const float4*)hr;
    float2 v1 = *(const float2*)(hr + 4);
    a0 += p * v0.x; a1 += p * v0.y; a2 += p * v0.z;
    a3 += p * v0.w; a4 += p * v1.x; a5 += p * v1.y;
  }
#pragma unroll
  for (int o = 1; o < 8; o <<= 1) {
    den += __shfl_xor(den, o);
    a0 += __shfl_xor(a0, o); a1 += __shfl_xor(a1, o); a2 += __shfl_xor(a2, o);
    a3 += __shfl_xor(a3, o); a4 += __shfl_xor(a4, o); a5 += __shfl_xor(a5, o);
  }
  if (sl == 0) {
    float v[CLS];
    v[0] = a0 / den + b2[0]; v[1] = a1 / den + b2[1]; v[2] = a2 / den + b2[2];
    v[3] = a3 / den + b2[3]; v[4] = a4 / den + b2[4]; v[5] = a5 / den + b2[5];
    float mx = -1e30f;
#pragma unroll
    for (int j = 0; j < CLS; ++j) mx = fmaxf(mx, v[j]);
    float sum = 0.f;
#pragma unroll
    for (int j = 0; j < CLS; ++j) sum += __expf(v[j] - mx);
    float l = mx + logf(sum);
#pragma unroll
    for (int j = 0; j < CLS; ++j) out[n * CLS + j] = v[j] - l;
  }
}

extern "C" void kernel_launch(void* const* d_in, const int* in_sizes, int n_in,
                              void* d_out, int out_size, void* d_ws, size_t ws_size,
                              hipStream_t stream) {
  const float* x      = (const float*)d_in[0];
  const int*   ei     = (const int*)d_in[1];
  const float* W1     = (const float*)d_in[2];
  const float* a_src1 = (const float*)d_in[3];
  const float* a_dst1 = (const float*)d_in[4];
  const float* b1     = (const float*)d_in[5];
  const float* W2     = (const float*)d_in[6];
  const float* a_src2 = (const float*)d_in[7];
  const float* a_dst2 = (const float*)d_in[8];
  const float* b2     = (const float*)d_in[9];
  float* out = (float*)d_out;

  const int IN_F = 512;
  int N = in_sizes[0] / IN_F;      // 50000
  int E = in_sizes[1] / 2;         // 800000
  int Etot = E + N;

  // ---- workspace partition ----
  float* ws = (float*)d_ws;
  size_t off = 0;
  ushort* h1b = (ushort*)(ws + off); off += (size_t)N * CH1;   // only half used
  float* es1  = ws + off; off += (size_t)N * HEADS;
  float* ed1  = ws + off; off += (size_t)N * HEADS;
  float* h2   = ws + off; off += (size_t)N * H2S;
  float* es2  = ws + off; off += (size_t)N;
  float* ed2  = ws + off; off += (size_t)N;
  int* rowptr = (int*)(ws + off); off += (size_t)N + 1;
  int* cursor = (int*)(ws + off); off += (size_t)N;
  int* bsum   = (int*)(ws + off); off += 256;
  int* esrc   = (int*)(ws + off); off += (size_t)Etot;
  ushort* w1t = (ushort*)(ws + off); off += (512 * 256 * 2 + 3) / 4;

  int nb = (N + 255) / 256;
  int eb = (Etot + 255) / 256;

  // ---- CSR build (by dst) + W1 cvt, merged where independent ----
  hipMemsetAsync(cursor, 0, (size_t)N * 4, stream);
  k_count_cvt<<<eb + 512, 256, 0, stream>>>(ei, E, Etot, cursor, eb, W1, w1t);
  k_scan1<<<nb, 256, 0, stream>>>(cursor, rowptr, bsum, N);  // also zeroes cursor
  k_scan3<<<nb, 256, 0, stream>>>(rowptr, bsum, N, Etot, nb);
  k_scatter<<<eb, 256, 0, stream>>>(ei, E, Etot, rowptr, cursor, esrc);

  // ---- layer 1 ----
  k_gemm1_mfma<<<((N + 63) / 64) * 2, 256, 0, stream>>>(x, w1t, a_src1, a_dst1,
                                                        h1b, es1, ed1, N);
  k_agg1_csr<<<(N + 3) / 4, 256, 0, stream>>>(rowptr, esrc, es1, ed1, h1b, b1,
                                              W2, a_src2, a_dst2, h2, es2, ed2, N);

  // ---- layer 2 ----
  k_l2<<<(N + 31) / 32, 256, 0, stream>>>(rowptr, esrc, es2, ed2, h2, b2, out, N);
}